// Round 6
// baseline (155.268 us; speedup 1.0000x reference)
//
#include <hip/hip_runtime.h>

// qpNet: h = x @ W^T + b ; z = max(-h, -1000). x:[B,5] f32, W:[5,5], b:[5].
// B = 4194304. 168 MB app traffic (84r+84w), HBM-counted ~126 MB (L3 absorbs
// ~42 MB of reads). Copy-rate floor ~20-27 us.
//
// R2:  80 B lane stride, one-shot      -> 57 us
// R3:  block LDS transpose + barrier   -> 50 us
// R6:  wave-private LDS transpose      -> ~50 us
// R7:  R6 + reg prefetch               -> 51.4 us (VGPR=28: prefetch sunk)
// R9:  no-LDS, 80 B stride             -> 61 us (stride + sunk prefetch)
// R10: R7 + sched_barrier pin          -> 49.6 us
// R11: global_load_lds dbuf, counted vmcnt(10), overlap GUARANTEED
//      -> 50.2 us. Depth/occupancy invariant: 5-15 outstanding/wave,
//      8-32 waves/CU, three structures, all 49.6-50.5 us.
// R12 (this): SHUFFLE KERNEL -- global pattern byte-identical to the 6.3 TB/s
//      copy ubench. Wave owns 240 floats = 48 rows (rows align to lanes every
//      5 lanes); lane's 4 outputs need a 12-float window = own f4 + neighbors
//      via 2x __shfl (no LDS alloc, no ds round trip, no waitcnt games).
//      Lane-varying row/weight alignment folded into per-lane zero-padded
//      Wt[4][12] + bq[4], built ONCE at init with compile-time indices
//      (5-way cndmask selects on lane%5; zero-weight fmas are exact, so
//      summation order and absmax are unchanged). Lanes 60-63 idle: 6% issue
//      slots, 0% bytes (240 floats = exactly 15 full 64B lines per access).
//      Grid-stride 2048 blocks, ~10 seg/wave.
//      FORK (pre-committed): 28-38 us => LDS chains were the cap.
//      ~50 us => 4 disjoint structures all pin at 50 => mixed-stream service
//      ceiling => ROOFLINE.

#define BLOCK 256
#define SEG_F4 60              // f4 per wave-segment = 240 floats = 48 rows

typedef float vf4 __attribute__((ext_vector_type(4)));

__global__ __launch_bounds__(BLOCK) void qpnet_kernel(
    const float* __restrict__ x,
    const float* __restrict__ W,
    const float* __restrict__ bfc,
    float* __restrict__ out,
    int total_f4)
{
    // 5x5 weights + bias (uniform -> scalar-cached).
    float w[5][5], bias[5];
#pragma unroll
    for (int j = 0; j < 5; ++j) {
        bias[j] = bfc[j];
#pragma unroll
        for (int i = 0; i < 5; ++i) w[j][i] = W[j * 5 + i];
    }

    const int lane = threadIdx.x & 63;
    const int wave = threadIdx.x >> 6;

    // Lane class within the 5-lane row group (lanes 60-63 are masked anyway).
    const int lq = lane % 5;
    const int s  = (4 * lq) % 5;        // (4*lane) mod 5
    // Window vw[0..11] = floats [4L-4, 4L+8). Output m = 4L+c has
    // j_c = (s+c)%5, and its row starts at window index
    // st_c = (s+c<5) ? 4-s : 9-s. Fold into zero-padded Wt[4][12]:
    //   dot_c = sum_k vw[k]*Wt[c][k],  Wt[c][k] = w[j_c][k-st_c] in range, else 0.
    // Built with ALL compile-time array indices (runtime only in cndmask
    // selects on s) -- rule #20 safe, stays in VGPRs.
    float Wt[4][12], bq[4];
#pragma unroll
    for (int c = 0; c < 4; ++c) {
        float bv = 0.0f;
#pragma unroll
        for (int k = 0; k < 12; ++k) Wt[c][k] = 0.0f;
#pragma unroll
        for (int sp = 0; sp < 5; ++sp) {
            const int  jj  = (sp + c) % 5;
            const int  st  = (sp + c < 5) ? (4 - sp) : (9 - sp);
            const bool sel = (s == sp);
            bv = sel ? bias[jj] : bv;
#pragma unroll
            for (int k = 0; k < 12; ++k) {
                if (k >= st && k < st + 5) {            // compile-time
                    const float cand = w[jj][k - st];   // compile-time idx
                    Wt[c][k] = sel ? cand : Wt[c][k];
                }
            }
        }
        bq[c] = bv;
    }

    const vf4* __restrict__ xin  = reinterpret_cast<const vf4*>(x);
    vf4* __restrict__       zout = reinterpret_cast<vf4*>(out);

    const int gwave = blockIdx.x * (BLOCK / 64) + wave;
    const int nwave = gridDim.x * (BLOCK / 64);
    const int nseg  = (total_f4 + SEG_F4 - 1) / SEG_F4;
    const int ll    = lane < 59 ? lane : 59;   // lanes 59-63 dup-load lane 59's
                                               // f4 (same addr -> merged, 0 bytes)

    for (int seg = gwave; seg < nseg; seg += nwave) {
        const int s60 = seg * SEG_F4;

        // ---- load: 16 B/lane, lane-contiguous, 15 full lines per wave instr
        int li = s60 + ll;
        if (li >= total_f4) li = total_f4 - 1;  // tail clamp (real data)
        const vf4 a = xin[li];

        // ---- 12-float window: left | own | right via intra-wave shuffles.
        // Out-of-range neighbors (lane 0 left, q=4 right) carry ZERO weight
        // in Wt, so garbage never contaminates.
        float vw[12];
#pragma unroll
        for (int k = 0; k < 4; ++k) {
            vw[4 + k] = a[k];
            vw[k]     = __shfl_up(a[k], 1);
            vw[8 + k] = __shfl_down(a[k], 1);
        }

        // ---- 4 outputs: 12-wide dots (5 real + 7 exact-zero fmas each)
        float zo[4];
#pragma unroll
        for (int c = 0; c < 4; ++c) {
            float acc = bq[c];
#pragma unroll
            for (int k = 0; k < 12; ++k) acc = fmaf(vw[k], Wt[c][k], acc);
            zo[c] = fmaxf(-acc, -1000.0f);
        }

        // ---- store: 16 B/lane, lane-contiguous, 15 full lines
        const int oi = s60 + lane;
        if (lane < 60 && oi < total_f4) {
            vf4 zv;
            zv[0] = zo[0]; zv[1] = zo[1]; zv[2] = zo[2]; zv[3] = zo[3];
            zout[oi] = zv;
        }
    }
}

extern "C" void kernel_launch(void* const* d_in, const int* in_sizes, int n_in,
                              void* d_out, int out_size, void* d_ws, size_t ws_size,
                              hipStream_t stream) {
    const float* x   = (const float*)d_in[0];   // [B,5]
    const float* W   = (const float*)d_in[1];   // [5,5]
    const float* bfc = (const float*)d_in[2];   // [5]
    float* out = (float*)d_out;                 // [B,5]

    int total_f4 = in_sizes[0] / 4;             // 5,242,880
    int nseg  = (total_f4 + SEG_F4 - 1) / SEG_F4;          // 87,382
    int nblk  = (nseg + (BLOCK / 64) - 1) / (BLOCK / 64);
    int grid  = nblk < 2048 ? nblk : 2048;                 // grid-stride

    qpnet_kernel<<<grid, BLOCK, 0, stream>>>(x, W, bfc, out, total_f4);
}

// Round 7
// 145.788 us; speedup vs baseline: 1.0650x; 1.0650x over previous
//
#include <hip/hip_runtime.h>

// qpNet: h = x @ W^T + b ; z = max(-h, -1000). x:[B,5] f32, W:[5,5], b:[5].
// B = 4194304. 168 MB app traffic (84r+84w); FETCH stable at 41 MB (half of
// x L3-resident), WRITE 84 MB. Copy-rate floor ~27 us.
//
// R2:  80 B lane stride, one-shot      -> 57 us
// R3:  block LDS transpose + barrier   -> 50 us
// R5:  nontemporal STORES              -> 82 us (WRITE 1.76x: nt defeats L2
//      write-combine at 16 B/lane granularity -- cache bits matter here!)
// R6:  wave-private LDS transpose      -> ~50 us
// R7:  R6 + reg prefetch               -> 51.4 us (VGPR=28: prefetch sunk)
// R9:  no-LDS, 80 B stride             -> 61 us
// R10: R7 + sched_barrier pin          -> 49.6 us  <- best
// R11: global_load_lds dbuf, counted vmcnt(10), overlap GUARANTEED -> 50.2 us
// R12: shuffle kernel, no LDS, copy-shaped, occ 50% -> 53.4 us
//   => FIVE disjoint structures, depth 5-15, occ 9-50%: all 49.6-53.5 us.
//      Structure exonerated. Effective READ stream rate ~1.7 TB/s while the
//      harness fill proves 6.7 TB/s writes in the same state.
// R13 (this): R10 byte-identical EXCEPT x loads are NONTEMPORAL (no-allocate,
//      evict-first). Theory: read-miss fill-allocate + store allocate/writeback
//      put ~290 MB/dispatch through the L3 crossbar (~44 us at the fill's
//      6.7 TB/s) -- the structure-invariant cap. nt loads remove the
//      fill-allocate component. Stores stay CACHED (R5 lesson).
//      Fork (pre-committed): <=45 us => cache-policy lever is real, iterate.
//      49-51 us => cache policy exonerated => ROOFLINE next round.

#define BLOCK 256
#define WAVES_PER_BLOCK 4          // BLOCK / 64
#define F4_PER_TILE 320            // 64 lanes * 5 f4 = 1280 floats = 256 rows
#define TILES_PER_WAVE 4           // 4096 waves total = 1024 blocks

typedef float vf4 __attribute__((ext_vector_type(4)));

__global__ __launch_bounds__(BLOCK) void qpnet_kernel(
    const float* __restrict__ x,
    const float* __restrict__ W,
    const float* __restrict__ bfc,
    float* __restrict__ out,
    int total_f4)
{
    __shared__ __align__(16) float lds[BLOCK * 20];   // 20 KB: 5 KB per wave

    // 5x5 weights + bias. Uniform addresses -> compiler scalarizes (s_load).
    float w[5][5];
    float bias[5];
#pragma unroll
    for (int j = 0; j < 5; ++j) {
        bias[j] = bfc[j];
#pragma unroll
        for (int i = 0; i < 5; ++i) w[j][i] = W[j * 5 + i];
    }

    const int wave = threadIdx.x >> 6;
    const int lane = threadIdx.x & 63;
    float* __restrict__ wlds = &lds[wave * (64 * 20)];   // this wave's 1280 floats

    const int wave_id = blockIdx.x * WAVES_PER_BLOCK + wave;
    const int tb = wave_id * (F4_PER_TILE * TILES_PER_WAVE);  // f4 units; fits int
    if (tb >= total_f4) return;                               // exact division

    const vf4* __restrict__ xin  = reinterpret_cast<const vf4*>(x);
    vf4* __restrict__       zout = reinterpret_cast<vf4*>(out);

    // ---- prologue: tile 0 loads (lane-contiguous, full-line, NONTEMPORAL)
    vf4 r[5];
#pragma unroll
    for (int k = 0; k < 5; ++k)
        r[k] = __builtin_nontemporal_load(&xin[tb + k * 64 + lane]);

#pragma unroll
    for (int t = 0; t < TILES_PER_WAVE; ++t) {
        const int cur = tb + t * F4_PER_TILE;

        // ---- stage current tile: regs -> LDS (waits vmcnt on r's loads only;
        // older stores may still be outstanding).
#pragma unroll
        for (int k = 0; k < 5; ++k)
            *reinterpret_cast<vf4*>(&wlds[(k * 64 + lane) * 4]) = r[k];

        // ---- issue NEXT tile's loads NOW (nontemporal), pinned by
        // sched_barrier(0) so the scheduler cannot sink them below.
        vf4 rn[5];
        if (t + 1 < TILES_PER_WAVE) {
            const int nxt = cur + F4_PER_TILE;
#pragma unroll
            for (int k = 0; k < 5; ++k)
                rn[k] = __builtin_nontemporal_load(&xin[nxt + k * 64 + lane]);
        }
        __builtin_amdgcn_sched_barrier(0);

        // Intra-wave exchange: SIMD lockstep + in-order DS pipe; drain lgkm
        // and fence the compiler (no __syncthreads needed, wave-private LDS).
        asm volatile("s_waitcnt lgkmcnt(0)" ::: "memory");

        // ---- transposed read: own 20 consecutive floats = 4 complete rows
        // (word addr lane*20 + 4p: stride-20 f4 groups cover all 32 banks / 8 lanes)
        float v[20];
#pragma unroll
        for (int p = 0; p < 5; ++p)
            *reinterpret_cast<vf4*>(&v[4 * p]) =
                *reinterpret_cast<const vf4*>(&wlds[lane * 20 + 4 * p]);

        // ---- compute: 4 rows x (5x5 matvec + bias + clamp), in place
#pragma unroll
        for (int k = 0; k < 4; ++k) {
            float t0 = bias[0], t1 = bias[1], t2 = bias[2], t3 = bias[3], t4 = bias[4];
#pragma unroll
            for (int i = 0; i < 5; ++i) {
                const float xv = v[k * 5 + i];
                t0 = fmaf(xv, w[0][i], t0);
                t1 = fmaf(xv, w[1][i], t1);
                t2 = fmaf(xv, w[2][i], t2);
                t3 = fmaf(xv, w[3][i], t3);
                t4 = fmaf(xv, w[4][i], t4);
            }
            v[k * 5 + 0] = fmaxf(-t0, -1000.0f);
            v[k * 5 + 1] = fmaxf(-t1, -1000.0f);
            v[k * 5 + 2] = fmaxf(-t2, -1000.0f);
            v[k * 5 + 3] = fmaxf(-t3, -1000.0f);
            v[k * 5 + 4] = fmaxf(-t4, -1000.0f);
        }

        // ---- transposed write back to own region
#pragma unroll
        for (int p = 0; p < 5; ++p)
            *reinterpret_cast<vf4*>(&wlds[lane * 20 + 4 * p]) =
                *reinterpret_cast<const vf4*>(&v[4 * p]);
        asm volatile("s_waitcnt lgkmcnt(0)" ::: "memory");

        // ---- stage out: LDS -> lane-contiguous global f4 stores, CACHED
        // (R5: nt stores at 16 B/lane granularity cause 1.76x write traffic).
#pragma unroll
        for (int k = 0; k < 5; ++k)
            zout[cur + k * 64 + lane] =
                *reinterpret_cast<const vf4*>(&wlds[(k * 64 + lane) * 4]);

        // hand prefetch to next iteration (full unroll -> SSA rename, no movs)
        if (t + 1 < TILES_PER_WAVE) {
#pragma unroll
            for (int k = 0; k < 5; ++k) r[k] = rn[k];
        }
    }
}

extern "C" void kernel_launch(void* const* d_in, const int* in_sizes, int n_in,
                              void* d_out, int out_size, void* d_ws, size_t ws_size,
                              hipStream_t stream) {
    const float* x   = (const float*)d_in[0];   // [B,5]
    const float* W   = (const float*)d_in[1];   // [5,5]
    const float* bfc = (const float*)d_in[2];   // [5]
    float* out = (float*)d_out;                 // [B,5]

    int total_f4 = in_sizes[0] / 4;             // 5,242,880
    int f4_per_wave = F4_PER_TILE * TILES_PER_WAVE;                    // 1280
    int n_waves  = (total_f4 + f4_per_wave - 1) / f4_per_wave;         // 4096
    int grid     = (n_waves + WAVES_PER_BLOCK - 1) / WAVES_PER_BLOCK;  // 1024

    qpnet_kernel<<<grid, BLOCK, 0, stream>>>(x, W, bfc, out, total_f4);
}